// Round 9
// baseline (328.009 us; speedup 1.0000x reference)
//
#include <hip/hip_runtime.h>

#define SW 63
#define DD 94

typedef __attribute__((ext_vector_type(8))) short  s8v;    // 8 bf16
typedef __attribute__((ext_vector_type(4))) float  f32x4;

// ws layout (bytes):
//   [0,    256K) : whf bf16 [2 dir][4 wv][8 nt][4 kt][64 lane][8]  (frag-ordered Wh')
//   [256K, 272K) : m1g f32  [2 dir][512 g'][4]  ({M1_c0,M1_c1,M1_c2,bias2})
//   [288K, 323K) : padtab f32 [2 dir][17 j][2 (h,c)][128 ch]
//   [512K, 896K) : owb bf16 [768][256]
//   [1M,   17M)  : comb bf16 [32 b][32 r][32 w][256 ch]
// g' = 4*ch + type (0=i,1=f,2=o,3=g); orig gate row = type*128 + ch.

__device__ __forceinline__ float sigmoid_f(float v) {
    return 1.0f / (1.0f + __expf(-v));
}
__device__ __forceinline__ float tanh_f(float v) {
    float e = __expf(2.0f * v);
    return 1.0f - 2.0f / (e + 1.0f);
}
__device__ __forceinline__ unsigned short f2bf(float f) {
    unsigned int u = __builtin_bit_cast(unsigned int, f);
    unsigned int r = (u + 0x7fffu + ((u >> 16) & 1u)) >> 16;
    return (unsigned short)r;
}

// ---- Wh fragments, gate-permuted ----
__global__ void prep_whf(const float* __restrict__ fwh, const float* __restrict__ bwh,
                         unsigned short* __restrict__ whf) {
    int dir = blockIdx.y;
    const float* src = dir ? bwh : fwh;
    int t = blockIdx.x * 256 + threadIdx.x;   // [0, 8192)
    int lane = t & 63;
    int kt   = (t >> 6) & 3;
    int nt   = (t >> 8) & 7;
    int wv   = (t >> 11) & 3;
    int gp  = wv * 128 + nt * 16 + (lane & 15);
    int row = (gp & 3) * 128 + (gp >> 2);
    int kb  = kt * 32 + (lane >> 4) * 8;
    const float* sr = src + row * 128 + kb;
    s8v v;
    #pragma unroll
    for (int j = 0; j < 8; j++) v[j] = (short)f2bf(sr[j]);
    *reinterpret_cast<s8v*>(whf + dir * 65536 + ((wv * 8 + nt) * 4 + kt) * 512 + lane * 8) = v;
}

// ---- M1 = Wi . ipw^T / 255  and  b2 = b + Wi . ipb ----
__global__ void prep_m1(const float* __restrict__ fwi, const float* __restrict__ bwi,
                        const float* __restrict__ fb,  const float* __restrict__ bb,
                        const float* __restrict__ ipw, const float* __restrict__ ipb,
                        float* __restrict__ m1g) {
    int t = blockIdx.x * 256 + threadIdx.x;   // [0,1024)
    int dir = t >> 9;
    int gp  = t & 511;
    const float* Wi = dir ? bwi : fwi;
    const float* bs = dir ? bb  : fb;
    int row = (gp & 3) * 128 + (gp >> 2);
    const float* wr = Wi + row * 128;
    float m0 = 0, m1 = 0, m2 = 0, b2 = bs[row];
    for (int k = 0; k < 128; k++) {
        float wv = wr[k];
        m0 += wv * ipw[k * 3 + 0];
        m1 += wv * ipw[k * 3 + 1];
        m2 += wv * ipw[k * 3 + 2];
        b2 += wv * ipb[k];
    }
    const float inv255 = 1.0f / 255.0f;
    float* d = m1g + (dir * 512 + gp) * 4;
    d[0] = m0 * inv255; d[1] = m1 * inv255; d[2] = m2 * inv255; d[3] = b2;
}

// ---- pad-state table: state after j zero-input steps (f32, matches reference) ----
__global__ void prep_padtab(const float* __restrict__ fwh, const float* __restrict__ bwh,
                            const float* __restrict__ fb,  const float* __restrict__ bb,
                            float* __restrict__ padtab) {   // [2][17][2][128]
    __shared__ float h_s[2][128], c_s[2][128], g_s[2][512];
    int tid = threadIdx.x;          // 0..1023
    int dir = tid >> 9;
    int go  = tid & 511;            // original gate row index
    const float* Wh = dir ? bwh : fwh;
    const float* bs = dir ? bb  : fb;
    float bias = bs[go];
    if (go < 128) {
        h_s[dir][go] = 0.0f; c_s[dir][go] = 0.0f;
        padtab[(dir * 17) * 256 + go] = 0.0f;
        padtab[(dir * 17) * 256 + 128 + go] = 0.0f;
    }
    __syncthreads();
    const float* wr = Wh + go * 128;
    for (int j = 1; j <= 16; j++) {
        float acc = bias;
        for (int k = 0; k < 128; k += 4) {
            float4 w4 = *(const float4*)(wr + k);
            acc += w4.x * h_s[dir][k] + w4.y * h_s[dir][k + 1]
                 + w4.z * h_s[dir][k + 2] + w4.w * h_s[dir][k + 3];
        }
        g_s[dir][go] = acc;
        __syncthreads();
        if (go < 128) {
            int ch = go;
            float gi = g_s[dir][ch], gf = g_s[dir][128 + ch];
            float gO = g_s[dir][256 + ch], gg = g_s[dir][384 + ch];
            float c = sigmoid_f(gf) * c_s[dir][ch] + sigmoid_f(gi) * tanh_f(gg);
            float h = sigmoid_f(gO) * tanh_f(c);
            h_s[dir][ch] = h; c_s[dir][ch] = c;
            padtab[(dir * 17 + j) * 256 + ch] = h;
            padtab[(dir * 17 + j) * 256 + 128 + ch] = c;
        }
        __syncthreads();
    }
}

__global__ void prep_ow(const float* __restrict__ ow, unsigned short* __restrict__ owb) {
    int i = blockIdx.x * 1024 + threadIdx.x;   // 0..196607
    owb[i] = f2bf(ow[i]);
}

// ---- LSTM over VALID cells only. Block = (d, dir, 16-batch half); 256 thr = 4 waves.
// Wave wv owns g' in [wv*128, wv*128+128). MFMA operand swap: A=Wh' (m=g'), B=h (n=seq).
// Lane (g16,cl): acc[nt][r] = gate type r of cell (seq=cl, ch=wv*32+nt*4+g16).
__global__ __launch_bounds__(256, 2) void lstm_diag(
    const float* __restrict__ x,        // (32,3,32,32)
    const unsigned short* __restrict__ whf,
    const float* __restrict__ m1g,      // [2][512][4]
    const float* __restrict__ padtab,   // [2][17][2][128]
    unsigned short* __restrict__ comb)  // [32768][256] bf16
{
    __shared__ unsigned short h_lds[2][16 * 128];   // 2 x 4KB, XOR-swizzled
    __shared__ float m1_s[512 * 4];                 // 8KB

    const int tid  = threadIdx.x;
    const int wv   = tid >> 6;
    const int lane = tid & 63;
    const int g16  = lane >> 4;
    const int cl   = lane & 15;
    const int swz  = (cl & 7) << 3;

    const int bidx = blockIdx.x;       // 376 = 94 d x 2 dir x 2 half
    const int d    = bidx >> 2;
    const int dir  = (bidx >> 1) & 1;
    const int bh   = bidx & 1;

    const int r0   = max(0, d - 62);
    const int rend = min(31, d);
    int a = d - 31;
    const int rlo = max(r0, (a > 0) ? ((a + 1) >> 1) : 0);
    const int rhi = min(rend, d >> 1);
    const int nv  = rhi - rlo + 1;                       // 1..16 valid cells
    const int jlead = dir ? (rend - rhi) : (rlo - r0);   // 0..16 leading pads

    // stage M1 for this dir
    {
        const f32x4* src = reinterpret_cast<const f32x4*>(m1g + dir * 2048);
        f32x4* dst = reinterpret_cast<f32x4*>(m1_s);
        dst[tid * 2]     = src[tid * 2];
        dst[tid * 2 + 1] = src[tid * 2 + 1];
    }
    // h0 from pad table (same for every sequence)
    {
        const float* ph = padtab + (dir * 17 + jlead) * 256;
        #pragma unroll
        for (int i = 0; i < 8; i++) {
            int l = tid * 8 + i;
            int seq = l >> 7, ch = l & 127;
            h_lds[0][l ^ ((seq & 7) << 3)] = f2bf(ph[ch]);
        }
    }
    // Wh fragments
    s8v whB[8][4];
    {
        const unsigned short* wp = whf + dir * 65536;
        #pragma unroll
        for (int nt = 0; nt < 8; nt++)
            #pragma unroll
            for (int kt = 0; kt < 4; kt++)
                whB[nt][kt] = *reinterpret_cast<const s8v*>(
                    wp + ((wv * 8 + nt) * 4 + kt) * 512 + lane * 8);
    }
    // c0 per lane (its 8 channels)
    float cst[8];
    {
        const float* pc = padtab + (dir * 17 + jlead) * 256 + 128;
        #pragma unroll
        for (int nt = 0; nt < 8; nt++) cst[nt] = pc[wv * 32 + nt * 4 + g16];
    }
    __syncthreads();

    const int b = bh * 16 + cl;
    const float* xb = x + b * 3072;

    // preload x(0)
    int rowp = dir ? rhi : rlo;
    int wp_  = d - 2 * rowp;
    float xv0 = xb[rowp * 32 + wp_];
    float xv1 = xb[1024 + rowp * 32 + wp_];
    float xv2 = xb[2048 + rowp * 32 + wp_];

    int cur = 0;
    for (int t = 0; t < nv; t++) {
        int rowc = dir ? (rhi - t) : (rlo + t);
        int wc_  = d - 2 * rowc;

        // C-init: b2 + x . M1 (exact f32)
        f32x4 acc[8];
        #pragma unroll
        for (int nt = 0; nt < 8; nt++) {
            #pragma unroll
            for (int r = 0; r < 4; r++) {
                f32x4 m = *reinterpret_cast<const f32x4*>(
                    &m1_s[(wv * 128 + nt * 16 + g16 * 4 + r) * 4]);
                acc[nt][r] = m[3] + xv0 * m[0] + xv1 * m[1] + xv2 * m[2];
            }
        }
        // MFMA: += Wh' . h   (K=128)
        #pragma unroll
        for (int kt = 0; kt < 4; kt++) {
            int idx = (cl * 128 + kt * 32 + g16 * 8) ^ swz;
            s8v hf = *reinterpret_cast<const s8v*>(&h_lds[cur][idx]);
            #pragma unroll
            for (int nt = 0; nt < 8; nt++)
                acc[nt] = __builtin_amdgcn_mfma_f32_16x16x32_bf16(whB[nt][kt], hf, acc[nt], 0, 0, 0);
        }
        // prefetch next x (covers L2 latency under pointwise+barrier)
        if (t + 1 < nv) {
            int rn = dir ? (rhi - t - 1) : (rlo + t + 1);
            int wn = d - 2 * rn;
            xv0 = xb[rn * 32 + wn];
            xv1 = xb[1024 + rn * 32 + wn];
            xv2 = xb[2048 + rn * 32 + wn];
        }
        // pointwise in-register; write h(t) + comb
        int nxt = cur ^ 1;
        unsigned int cbase = ((unsigned)(b * 32 + rowc) * 32 + wc_) * 256 + dir * 128;
        #pragma unroll
        for (int nt = 0; nt < 8; nt++) {
            int ch = wv * 32 + nt * 4 + g16;
            float gi = acc[nt][0], gf = acc[nt][1], gO = acc[nt][2], gg = acc[nt][3];
            float c = sigmoid_f(gf) * cst[nt] + sigmoid_f(gi) * tanh_f(gg);
            cst[nt] = c;
            float hn = sigmoid_f(gO) * tanh_f(c);
            unsigned short hq = f2bf(hn);
            h_lds[nxt][(cl * 128 + ch) ^ swz] = hq;
            comb[cbase + ch] = hq;
        }
        __syncthreads();
        cur = nxt;
    }
}

// ---- out projection: bf16 MFMA, M=32768 cells x N=768 x K=256, full-line stores ----
__global__ __launch_bounds__(256) void outproj_mfma(
    const unsigned short* __restrict__ comb,   // [32768][256] bf16
    const unsigned short* __restrict__ owb,    // [768][256] bf16
    const float* __restrict__ ob,              // [768]
    float* __restrict__ out)                   // [32][768][1024] f32
{
    __shared__ float ep[32 * 132];

    const int tid  = threadIdx.x;
    const int wave = tid >> 6;
    const int wo   = wave >> 1;
    const int wc   = wave & 1;
    const int lane = tid & 63;
    const int g16  = lane >> 4;
    const int cl   = lane & 15;

    const int o_base = blockIdx.y * 128 + wo * 64;
    const int c_base = blockIdx.x * 128 + wc * 64;

    f32x4 acc[4][4];
    #pragma unroll
    for (int of = 0; of < 4; of++)
        #pragma unroll
        for (int cf = 0; cf < 4; cf++) {
            f32x4 z = {0.f, 0.f, 0.f, 0.f};
            acc[of][cf] = z;
        }

    for (int kt = 0; kt < 8; kt++) {
        int kb = kt * 32 + g16 * 8;
        s8v av[4], bv[4];
        #pragma unroll
        for (int of = 0; of < 4; of++)
            av[of] = *reinterpret_cast<const s8v*>(owb + (o_base + of * 16 + cl) * 256 + kb);
        #pragma unroll
        for (int cf = 0; cf < 4; cf++)
            bv[cf] = *reinterpret_cast<const s8v*>(comb + (c_base + cf * 16 + cl) * 256 + kb);
        #pragma unroll
        for (int of = 0; of < 4; of++)
            #pragma unroll
            for (int cf = 0; cf < 4; cf++)
                acc[of][cf] = __builtin_amdgcn_mfma_f32_16x16x32_bf16(av[of], bv[cf], acc[of][cf], 0, 0, 0);
    }

    // epilogue: LDS transpose -> float4 stores covering full 128B lines
    const int bi  = (blockIdx.x * 128) >> 10;
    const int rwb = (blockIdx.x * 128) & 1023;
    #pragma unroll
    for (int of = 0; of < 4; of++) {
        __syncthreads();
        #pragma unroll
        for (int cf = 0; cf < 4; cf++)
            #pragma unroll
            for (int r = 0; r < 4; r++)
                ep[(wo * 16 + g16 * 4 + r) * 132 + wc * 64 + cf * 16 + cl] = acc[of][cf][r];
        __syncthreads();
        int o_loc = tid >> 3;
        int cs    = (tid & 7) * 16;
        int o     = blockIdx.y * 128 + (o_loc >> 4) * 64 + of * 16 + (o_loc & 15);
        float bo  = ob[o];
        float* op = out + (bi * 768 + o) * 1024 + rwb + cs;
        #pragma unroll
        for (int i = 0; i < 4; i++) {
            f32x4 v = *reinterpret_cast<const f32x4*>(&ep[o_loc * 132 + cs + i * 4]);
            v[0] += bo; v[1] += bo; v[2] += bo; v[3] += bo;
            *reinterpret_cast<f32x4*>(op + i * 4) = v;
        }
    }
}

extern "C" void kernel_launch(void* const* d_in, const int* in_sizes, int n_in,
                              void* d_out, int out_size, void* d_ws, size_t ws_size,
                              hipStream_t stream) {
    const float* x      = (const float*)d_in[0];
    const float* ipw    = (const float*)d_in[1];
    const float* ipb    = (const float*)d_in[2];
    const float* fwd_Wi = (const float*)d_in[3];
    const float* fwd_Wh = (const float*)d_in[4];
    const float* fwd_b  = (const float*)d_in[5];
    const float* bwd_Wi = (const float*)d_in[6];
    const float* bwd_Wh = (const float*)d_in[7];
    const float* bwd_b  = (const float*)d_in[8];
    const float* out_w  = (const float*)d_in[9];
    const float* out_b  = (const float*)d_in[10];

    char* ws = (char*)d_ws;
    unsigned short* whf    = (unsigned short*)(ws);                 // 256 KB
    float*          m1g    = (float*)(ws + (256 << 10));            // 16 KB
    float*          padtab = (float*)(ws + (288 << 10));            // 34 KB
    unsigned short* owb    = (unsigned short*)(ws + (512 << 10));   // 384 KB
    unsigned short* comb   = (unsigned short*)(ws + (1 << 20));     // 16 MB
    float*          out    = (float*)d_out;

    hipLaunchKernelGGL(prep_whf, dim3(32, 2), dim3(256), 0, stream,
                       fwd_Wh, bwd_Wh, whf);
    hipLaunchKernelGGL(prep_m1, dim3(4), dim3(256), 0, stream,
                       fwd_Wi, bwd_Wi, fwd_b, bwd_b, ipw, ipb, m1g);
    hipLaunchKernelGGL(prep_padtab, dim3(1), dim3(1024), 0, stream,
                       fwd_Wh, bwd_Wh, fwd_b, bwd_b, padtab);
    hipLaunchKernelGGL(prep_ow, dim3(192), dim3(1024), 0, stream,
                       out_w, owb);

    hipLaunchKernelGGL(lstm_diag, dim3(DD * 4), dim3(256), 0, stream,
                       x, whf, m1g, padtab, comb);

    hipLaunchKernelGGL(outproj_mfma, dim3(256, 6), dim3(256), 0, stream,
                       comb, owb, out_b, out);
}